// Round 10
// baseline (1417.251 us; speedup 1.0000x reference)
//
#include <hip/hip_runtime.h>
#include <math.h>

// Sinkhorn regularized transport, B=8, m=n=1024, fp32, 100 iterations.
//
// Round 10: dual-batch interleave on the verified R4 agent-scope protocol.
//
// Evidence trail:
//  R4 (best, 536us = 5.3us/iter): ~1.9us compute + ~3.4us serialized L3 RTT
//      chain (drain, stampA publish+detect, 4KB read, v publish+drain,
//      stampV detect, 4KB read).
//  R5/R7: RTT COUNT can't be cut (data-line polling streams at HBM; fused
//      atomicAdd reduce serializes 32-way per line).
//  R8/R9: RTT LENGTH can't be cut (XCD-local sc0 comm deadlocked; only
//      agent-scope __hip_atomic ops are verified for cross-block signaling).
//  => HIDE the RTTs: each block serves TWO batches (16 rows each, 64 blocks
//     per batch). The two chains' polls overlap the other chain's work:
//     pollA_Y hides behind reduceX, pollV_X behind reduceY, pollV_Y behind
//     compB_X. Per-CU compute is unchanged (32 rows total).
//  Single-buffered part/v (proof: a block writes partials(t+1) only after
//  consuming v(t), which requires every owner to have finished reading
//  partials(t) and every block to have read v(t)). Stamps monotonic, polls
//  on dedicated flag lines only, bulk data read exactly once.

#define B_    8
#define N_    1024
#define NP    4          // batch pairs
#define G2    64         // blocks per batch (fan-in)
#define RPB2  16         // rows per block per batch
#define KSTR  1028       // LDS row stride: 16B-aligned, bank skew
#define NITER 100
#define TPB   256
#define LMB   10.0f
#define MAXD  5.0f

// LDS: KX,KY (2*RPB2*KSTR) + vlX,vlY (2*N_) + ulX,ulY (2*RPB2) + red (32 f4)
#define LDS_FLOATS (2 * RPB2 * KSTR + 2 * N_ + 2 * RPB2 + 4 * 32)

typedef unsigned long long u64;

__device__ __forceinline__ void st8(float* p, float a, float b) {
    float2 f2 = make_float2(a, b);
    __hip_atomic_store((u64*)p, __builtin_bit_cast(u64, f2),
                       __ATOMIC_RELAXED, __HIP_MEMORY_SCOPE_AGENT);
}
__device__ __forceinline__ float2 ld8(const float* p) {
    u64 raw = __hip_atomic_load((const u64*)p,
                                __ATOMIC_RELAXED, __HIP_MEMORY_SCOPE_AGENT);
    return __builtin_bit_cast(float2, raw);
}
__device__ __forceinline__ void publish(int* s, int v) {
    __atomic_signal_fence(__ATOMIC_SEQ_CST);
    __hip_atomic_store(s, v, __ATOMIC_RELAXED, __HIP_MEMORY_SCOPE_AGENT);
}
// Wait until all 64 stamps reach tgt: one coalesced 256B flag read per poll.
__device__ __forceinline__ void poll64(const int* st, int tgt) {
    const int l = threadIdx.x & 63;
    for (;;) {
        int s = __hip_atomic_load(&st[l], __ATOMIC_RELAXED,
                                  __HIP_MEMORY_SCOPE_AGENT);
        if (__all(s >= tgt)) break;
        __builtin_amdgcn_s_sleep(1);
    }
    __atomic_signal_fence(__ATOMIC_SEQ_CST);
}

__global__ void __launch_bounds__(TPB, 1)
sinkhorn_kernel(const float* __restrict__ Mg,
                float* __restrict__ Pg,
                float* __restrict__ part,    // [B_][G2][N_] single-buffered
                float* __restrict__ vbuf,    // [B_][N_]     single-buffered
                int* __restrict__ stA,       // [B_][G2] monotonic stamps
                int* __restrict__ stV)       // [B_][G2]
{
    extern __shared__ float lds[];
    float* KX   = lds;                          // RPB2 x KSTR
    float* KY   = KX + RPB2 * KSTR;             // RPB2 x KSTR
    float* vlX  = KY + RPB2 * KSTR;             // N_
    float* vlY  = vlX + N_;                     // N_
    float* ulX  = vlY + N_;                     // RPB2
    float* ulY  = ulX + RPB2;                   // RPB2
    float4* redX = (float4*)(ulY + RPB2);       // 16 float4
    float4* redY = redX + 16;                   // 16 float4

    const int pr   = blockIdx.x & (NP - 1);
    const int g    = blockIdx.x >> 2;           // 0..63
    const int bx   = 2 * pr;
    const int by   = 2 * pr + 1;
    const int t    = threadIdx.x;
    const int row0 = g * RPB2;
    const float r = 1.0f / (float)N_;
    const float c = 1.0f / (float)N_;

    // ---- stage K rows for both batches into LDS ----
    const float* MbX = Mg + ((size_t)bx * N_ + row0) * N_;
    const float* MbY = Mg + ((size_t)by * N_ + row0) * N_;
    for (int i = 0; i < RPB2; ++i) {
        float4 mx = ((const float4*)(MbX + (size_t)i * N_))[t];
        float4 my = ((const float4*)(MbY + (size_t)i * N_))[t];
        float4 kx, ky;
        kx.x = expf(-LMB * fminf(mx.x, MAXD));
        kx.y = expf(-LMB * fminf(mx.y, MAXD));
        kx.z = expf(-LMB * fminf(mx.z, MAXD));
        kx.w = expf(-LMB * fminf(mx.w, MAXD));
        ky.x = expf(-LMB * fminf(my.x, MAXD));
        ky.y = expf(-LMB * fminf(my.y, MAXD));
        ky.z = expf(-LMB * fminf(my.z, MAXD));
        ky.w = expf(-LMB * fminf(my.w, MAXD));
        *(float4*)&KX[i * KSTR + 4 * t] = kx;
        *(float4*)&KY[i * KSTR + 4 * t] = ky;
    }
    if (t < RPB2) { ulX[t] = r; ulY[t] = r; }
    __syncthreads();

    int* stA_x = stA + bx * G2;
    int* stA_y = stA + by * G2;
    int* stV_x = stV + bx * G2;
    int* stV_y = stV + by * G2;
    float* pxs = part + (size_t)(bx * G2 + g) * N_;
    float* pys = part + (size_t)(by * G2 + g) * N_;
    float* vbX = vbuf + (size_t)bx * N_;
    float* vbY = vbuf + (size_t)by * N_;

    for (int it = 0; it <= NITER; ++it) {
        const int tgt = it + 1;

        // ---- phase A, both batches: partial[j] = sum_i K[i][j]*u_i ----
        {
            float4 aX = make_float4(0.f, 0.f, 0.f, 0.f);
            float4 aY = make_float4(0.f, 0.f, 0.f, 0.f);
#pragma unroll
            for (int i = 0; i < RPB2; ++i) {
                const float ux = ulX[i], uy = ulY[i];
                const float4 kx = *(const float4*)&KX[i * KSTR + 4 * t];
                const float4 ky = *(const float4*)&KY[i * KSTR + 4 * t];
                aX.x = fmaf(kx.x, ux, aX.x); aX.y = fmaf(kx.y, ux, aX.y);
                aX.z = fmaf(kx.z, ux, aX.z); aX.w = fmaf(kx.w, ux, aX.w);
                aY.x = fmaf(ky.x, uy, aY.x); aY.y = fmaf(ky.y, uy, aY.y);
                aY.z = fmaf(ky.z, uy, aY.z); aY.w = fmaf(ky.w, uy, aY.w);
            }
            st8(&pxs[4 * t],     aX.x, aX.y);
            st8(&pxs[4 * t + 2], aX.z, aX.w);
            st8(&pys[4 * t],     aY.x, aY.y);
            st8(&pys[4 * t + 2], aY.z, aY.w);
        }
        __syncthreads();                 // vmcnt(0) in every wave, then barrier
        if (t == 0) { publish(&stA_x[g], tgt); publish(&stA_y[g], tgt); }

        // ---- owner-reduce: block g owns cols [16g,16g+16) of BOTH batches
        poll64(stA_x, tgt);
        {
            const int gp = t >> 2, q = t & 3;
            const float* pb = part + (size_t)(bx * G2 + gp) * N_
                            + 16 * g + 4 * q;
            float2 s0 = ld8(pb), s1 = ld8(pb + 2);
            float4 acc = make_float4(s0.x, s0.y, s1.x, s1.y);
#pragma unroll
            for (int d = 4; d <= 32; d <<= 1) {
                acc.x += __shfl_xor(acc.x, d);
                acc.y += __shfl_xor(acc.y, d);
                acc.z += __shfl_xor(acc.z, d);
                acc.w += __shfl_xor(acc.w, d);
            }
            if ((t & 63) < 4) redX[(t >> 6) * 4 + (t & 63)] = acc;
        }
        poll64(stA_y, tgt);              // detect hides behind reduceX
        {
            const int gp = t >> 2, q = t & 3;
            const float* pb = part + (size_t)(by * G2 + gp) * N_
                            + 16 * g + 4 * q;
            float2 s0 = ld8(pb), s1 = ld8(pb + 2);
            float4 acc = make_float4(s0.x, s0.y, s1.x, s1.y);
#pragma unroll
            for (int d = 4; d <= 32; d <<= 1) {
                acc.x += __shfl_xor(acc.x, d);
                acc.y += __shfl_xor(acc.y, d);
                acc.z += __shfl_xor(acc.z, d);
                acc.w += __shfl_xor(acc.w, d);
            }
            if ((t & 63) < 4) redY[(t >> 6) * 4 + (t & 63)] = acc;
        }
        __syncthreads();
        if (t < 4) {
            float4 y4;
            y4.x = redX[t].x + redX[4 + t].x + redX[8 + t].x + redX[12 + t].x;
            y4.y = redX[t].y + redX[4 + t].y + redX[8 + t].y + redX[12 + t].y;
            y4.z = redX[t].z + redX[4 + t].z + redX[8 + t].z + redX[12 + t].z;
            y4.w = redX[t].w + redX[4 + t].w + redX[8 + t].w + redX[12 + t].w;
            st8(&vbX[16 * g + 4 * t],     c / y4.x, c / y4.y);
            st8(&vbX[16 * g + 4 * t + 2], c / y4.z, c / y4.w);
        } else if (t < 8) {
            const int i = t - 4;
            float4 y4;
            y4.x = redY[i].x + redY[4 + i].x + redY[8 + i].x + redY[12 + i].x;
            y4.y = redY[i].y + redY[4 + i].y + redY[8 + i].y + redY[12 + i].y;
            y4.z = redY[i].z + redY[4 + i].z + redY[8 + i].z + redY[12 + i].z;
            y4.w = redY[i].w + redY[4 + i].w + redY[8 + i].w + redY[12 + i].w;
            st8(&vbY[16 * g + 4 * i],     c / y4.x, c / y4.y);
            st8(&vbY[16 * g + 4 * i + 2], c / y4.z, c / y4.w);
        }
        if (t == 0) {                    // lanes 0..7 are wave 0: one drain
            __atomic_signal_fence(__ATOMIC_SEQ_CST);
            __builtin_amdgcn_s_waitcnt(0);
            publish(&stV_x[g], tgt); publish(&stV_y[g], tgt);
        }

        // ---- consume vX, compB_X (hides pollV_Y's RTT) ----
        poll64(stV_x, tgt);
        {
            float2 w0 = ld8(&vbX[4 * t]), w1 = ld8(&vbX[4 * t + 2]);
            *(float4*)&vlX[4 * t] = make_float4(w0.x, w0.y, w1.x, w1.y);
        }
        __syncthreads();
        if (it < NITER) {
            const int rI = t >> 4, l = t & 15;
            float z = 0.f;
#pragma unroll
            for (int k = 0; k < 16; ++k) {
                const int j0 = 4 * l + 64 * k;
                const float4 kx = *(const float4*)&KX[rI * KSTR + j0];
                const float4 vv = *(const float4*)&vlX[j0];
                z = fmaf(kx.x, vv.x, z); z = fmaf(kx.y, vv.y, z);
                z = fmaf(kx.z, vv.z, z); z = fmaf(kx.w, vv.w, z);
            }
            z += __shfl_xor(z, 1); z += __shfl_xor(z, 2);
            z += __shfl_xor(z, 4); z += __shfl_xor(z, 8);
            if (l == 0) ulX[rI] = r / z;
        }

        // ---- consume vY, compB_Y ----
        poll64(stV_y, tgt);
        {
            float2 w0 = ld8(&vbY[4 * t]), w1 = ld8(&vbY[4 * t + 2]);
            *(float4*)&vlY[4 * t] = make_float4(w0.x, w0.y, w1.x, w1.y);
        }
        __syncthreads();
        if (it == NITER) break;          // vlX/vlY hold final v; ul final u
        {
            const int rI = t >> 4, l = t & 15;
            float z = 0.f;
#pragma unroll
            for (int k = 0; k < 16; ++k) {
                const int j0 = 4 * l + 64 * k;
                const float4 ky = *(const float4*)&KY[rI * KSTR + j0];
                const float4 vv = *(const float4*)&vlY[j0];
                z = fmaf(ky.x, vv.x, z); z = fmaf(ky.y, vv.y, z);
                z = fmaf(ky.z, vv.z, z); z = fmaf(ky.w, vv.w, z);
            }
            z += __shfl_xor(z, 1); z += __shfl_xor(z, 2);
            z += __shfl_xor(z, 4); z += __shfl_xor(z, 8);
            if (l == 0) ulY[rI] = r / z;
        }
        __syncthreads();
    }

    // ---- epilogue: P[i][j] = u_i * K[i][j] * v_j, both batches ----
    float* PbX = Pg + ((size_t)bx * N_ + row0) * N_;
    float* PbY = Pg + ((size_t)by * N_ + row0) * N_;
    const float4 vx = *(const float4*)&vlX[4 * t];
    const float4 vy = *(const float4*)&vlY[4 * t];
    for (int i = 0; i < RPB2; ++i) {
        const float ux = ulX[i], uy = ulY[i];
        const float4 kx = *(const float4*)&KX[i * KSTR + 4 * t];
        const float4 ky = *(const float4*)&KY[i * KSTR + 4 * t];
        float4 px, py;
        px.x = ux * kx.x * vx.x; px.y = ux * kx.y * vx.y;
        px.z = ux * kx.z * vx.z; px.w = ux * kx.w * vx.w;
        py.x = uy * ky.x * vy.x; py.y = uy * ky.y * vy.y;
        py.z = uy * ky.z * vy.z; py.w = uy * ky.w * vy.w;
        ((float4*)(PbX + (size_t)i * N_))[t] = px;
        ((float4*)(PbY + (size_t)i * N_))[t] = py;
    }
}

extern "C" void kernel_launch(void* const* d_in, const int* in_sizes, int n_in,
                              void* d_out, int out_size, void* d_ws, size_t ws_size,
                              hipStream_t stream) {
    const float* M = (const float*)d_in[0];
    float* P = (float*)d_out;

    const size_t part_floats = (size_t)B_ * G2 * N_;   // 2 MB
    const size_t v_floats    = (size_t)B_ * N_;        // 32 KB
    float* part = (float*)d_ws;
    float* vbuf = part + part_floats;
    int*   stA  = (int*)(vbuf + v_floats);
    int*   stV  = stA + B_ * G2;
    // stamps must start at 0 every launch (part/vbuf are stamp-gated)
    (void)hipMemsetAsync(stA, 0, (size_t)2 * B_ * G2 * sizeof(int), stream);

    const size_t lds_bytes = (size_t)LDS_FLOATS * sizeof(float);
    (void)hipFuncSetAttribute((const void*)sinkhorn_kernel,
                              hipFuncAttributeMaxDynamicSharedMemorySize,
                              (int)lds_bytes);

    void* args[] = { (void*)&M, (void*)&P, (void*)&part, (void*)&vbuf,
                     (void*)&stA, (void*)&stV };
    hipError_t e = hipLaunchCooperativeKernel((void*)sinkhorn_kernel,
                                              dim3(B_ * 32), dim3(TPB),
                                              args, (unsigned)lds_bytes, stream);
    if (e != hipSuccess) {
        // fallback: 256 blocks at 1 block/CU (LDS-forced) on 256 CUs is
        // co-resident, which the stamp-flag dataflow requires
        sinkhorn_kernel<<<dim3(B_ * 32), dim3(TPB), lds_bytes, stream>>>(
            M, P, part, vbuf, stA, stV);
    }
}